// Round 3
// baseline (37.490 us; speedup 1.0000x reference)
//
#include <hip/hip_runtime.h>

constexpr int IMG_H = 2048;
constexpr int IMG_W = 2048;

// compare-exchange: a=min, b=max
#define CE(a, b) { float _mn = fminf(a, b); b = fmaxf(a, b); a = _mn; }

__device__ __forceinline__ void sw14(float& a0, float& a1, float& a2, float& a3, float& a4,
                                     float& a5, float& a6, float& a7, float& a8, float& a9,
                                     float& a10, float& a11, float& a12, float& a13) {
    CE(a0, a13) CE(a1, a12) CE(a2, a11) CE(a3, a10) CE(a4, a9) CE(a5, a8) CE(a6, a7)
    CE(a0, a1) CE(a0, a2) CE(a0, a3) CE(a0, a4) CE(a0, a5) CE(a0, a6)
    CE(a6, a13) CE(a7, a13) CE(a8, a13) CE(a9, a13) CE(a10, a13) CE(a11, a13) CE(a12, a13)
}
__device__ __forceinline__ void sw13(float& a0, float& a1, float& a2, float& a3, float& a4,
                                     float& a5, float& a6, float& a7, float& a8, float& a9,
                                     float& a10, float& a11, float& a12) {
    CE(a0, a12) CE(a1, a11) CE(a2, a10) CE(a3, a9) CE(a4, a8) CE(a5, a7)
    CE(a0, a1) CE(a0, a2) CE(a0, a3) CE(a0, a4) CE(a0, a5) CE(a0, a6)
    CE(a6, a12) CE(a7, a12) CE(a8, a12) CE(a9, a12) CE(a10, a12) CE(a11, a12)
}
__device__ __forceinline__ void sw12(float& a0, float& a1, float& a2, float& a3, float& a4,
                                     float& a5, float& a6, float& a7, float& a8, float& a9,
                                     float& a10, float& a11) {
    CE(a0, a11) CE(a1, a10) CE(a2, a9) CE(a3, a8) CE(a4, a7) CE(a5, a6)
    CE(a0, a1) CE(a0, a2) CE(a0, a3) CE(a0, a4) CE(a0, a5)
    CE(a5, a11) CE(a6, a11) CE(a7, a11) CE(a8, a11) CE(a9, a11) CE(a10, a11)
}
__device__ __forceinline__ void sw11(float& a0, float& a1, float& a2, float& a3, float& a4,
                                     float& a5, float& a6, float& a7, float& a8, float& a9,
                                     float& a10) {
    CE(a0, a10) CE(a1, a9) CE(a2, a8) CE(a3, a7) CE(a4, a6)
    CE(a0, a1) CE(a0, a2) CE(a0, a3) CE(a0, a4) CE(a0, a5)
    CE(a5, a10) CE(a6, a10) CE(a7, a10) CE(a8, a10) CE(a9, a10)
}
__device__ __forceinline__ void sw10(float& a0, float& a1, float& a2, float& a3, float& a4,
                                     float& a5, float& a6, float& a7, float& a8, float& a9) {
    CE(a0, a9) CE(a1, a8) CE(a2, a7) CE(a3, a6) CE(a4, a5)
    CE(a0, a1) CE(a0, a2) CE(a0, a3) CE(a0, a4)
    CE(a4, a9) CE(a5, a9) CE(a6, a9) CE(a7, a9) CE(a8, a9)
}
__device__ __forceinline__ void sw9(float& a0, float& a1, float& a2, float& a3, float& a4,
                                    float& a5, float& a6, float& a7, float& a8) {
    CE(a0, a8) CE(a1, a7) CE(a2, a6) CE(a3, a5)
    CE(a0, a1) CE(a0, a2) CE(a0, a3) CE(a0, a4)
    CE(a4, a8) CE(a5, a8) CE(a6, a8) CE(a7, a8)
}
__device__ __forceinline__ void sw8(float& a0, float& a1, float& a2, float& a3, float& a4,
                                    float& a5, float& a6, float& a7) {
    CE(a0, a7) CE(a1, a6) CE(a2, a5) CE(a3, a4)
    CE(a0, a1) CE(a0, a2) CE(a0, a3)
    CE(a3, a7) CE(a4, a7) CE(a5, a7) CE(a6, a7)
}
__device__ __forceinline__ void sw7(float& a0, float& a1, float& a2, float& a3, float& a4,
                                    float& a5, float& a6) {
    CE(a0, a6) CE(a1, a5) CE(a2, a4)
    CE(a0, a1) CE(a0, a2) CE(a0, a3)
    CE(a3, a6) CE(a4, a6) CE(a5, a6)
}
__device__ __forceinline__ void sw6(float& a0, float& a1, float& a2, float& a3, float& a4,
                                    float& a5) {
    CE(a0, a5) CE(a1, a4) CE(a2, a3)
    CE(a0, a1) CE(a0, a2)
    CE(a2, a5) CE(a3, a5) CE(a4, a5)
}

// tail for one pixel: 8 shared survivors (ranks 7..14 of shared 20) + 5 private -> median
__device__ __forceinline__ float tail5(float l1, float l2, float l3, float l4, float l5,
                                       float l6, float l7, float l8,
                                       float p0, float p1, float p2, float p3, float p4) {
    float l0 = p0;
    sw9(l0, l1, l2, l3, l4, l5, l6, l7, l8);
    l0 = p1;
    sw8(l0, l1, l2, l3, l4, l5, l6, l7);
    l0 = p2;
    sw7(l0, l1, l2, l3, l4, l5, l6);
    l0 = p3;
    sw6(l0, l1, l2, l3, l4, l5);
    l0 = p4;
    // 5 survivors hold ranks 11..15 of 25 -> median of 5
    CE(l0, l1) CE(l3, l4) CE(l0, l3) CE(l1, l4)
    return __builtin_amdgcn_fmed3f(l1, l2, l3);
}

__global__ __launch_bounds__(256, 2) void median5x5_kernel(const float* __restrict__ img,
                                                           float* __restrict__ out) {
    const int t = blockIdx.x * blockDim.x + threadIdx.x;  // pixel-pair index
    const int y = blockIdx.y * blockDim.y + threadIdx.y;
    const int xL = 2 * t;  // left pixel; right = xL+1

    // reflected row bases
    int r0 = y - 2, r1 = y - 1, r3 = y + 1, r4 = y + 2;
    r0 = (r0 < 0) ? -r0 : r0;
    r1 = (r1 < 0) ? -r1 : r1;
    r3 = (r3 >= IMG_H) ? 2 * IMG_H - 2 - r3 : r3;
    r4 = (r4 >= IMG_H) ? 2 * IMG_H - 2 - r4 : r4;
    const int ry0 = r0 * IMG_W, ry1 = r1 * IMG_W, ry2 = y * IMG_W,
              ry3 = r3 * IMG_W, ry4 = r4 * IMG_W;

    // per-row 6-tuples: [p, s1, s2, s3, s4, q]  (cols xL-2 .. xL+3 reflected)
    float a0, a1, a2, a3, a4, a5;  // row0
    float b0, b1, b2, b3, b4, b5;  // row1
    float c0v, c1v, c2v, c3v, c4v, c5v;  // row2
    float d0, d1, d2, d3, d4, d5;  // row3
    float e0, e1, e2, e3, e4, e5;  // row4

    const bool interior = (xL >= 2) & (xL + 3 < IMG_W);
    if (interior) {
        // xL even, xL-2 >= 0 -> 8B-aligned float2 loads, 3 per row
#define LOADROW(base, v0, v1, v2, v3, v4, v5)                                   \
        {                                                                       \
            const float2 A = *reinterpret_cast<const float2*>(img + (base) + xL - 2); \
            const float2 B = *reinterpret_cast<const float2*>(img + (base) + xL);     \
            const float2 C = *reinterpret_cast<const float2*>(img + (base) + xL + 2); \
            v0 = A.x; v1 = A.y; v2 = B.x; v3 = B.y; v4 = C.x; v5 = C.y;         \
        }
        LOADROW(ry0, a0, a1, a2, a3, a4, a5)
        LOADROW(ry1, b0, b1, b2, b3, b4, b5)
        LOADROW(ry2, c0v, c1v, c2v, c3v, c4v, c5v)
        LOADROW(ry3, d0, d1, d2, d3, d4, d5)
        LOADROW(ry4, e0, e1, e2, e3, e4, e5)
#undef LOADROW
    } else {
        int c0 = xL - 2, c1 = xL - 1, c4 = xL + 2, c5 = xL + 3;
        c0 = (c0 < 0) ? -c0 : c0;
        c1 = (c1 < 0) ? -c1 : c1;
        c4 = (c4 >= IMG_W) ? 2 * IMG_W - 2 - c4 : c4;
        c5 = (c5 >= IMG_W) ? 2 * IMG_W - 2 - c5 : c5;
        const int c2 = xL, c3 = xL + 1;
#define LOADROW(base, v0, v1, v2, v3, v4, v5)                 \
        {                                                     \
            v0 = img[(base) + c0]; v1 = img[(base) + c1];     \
            v2 = img[(base) + c2]; v3 = img[(base) + c3];     \
            v4 = img[(base) + c4]; v5 = img[(base) + c5];     \
        }
        LOADROW(ry0, a0, a1, a2, a3, a4, a5)
        LOADROW(ry1, b0, b1, b2, b3, b4, b5)
        LOADROW(ry2, c0v, c1v, c2v, c3v, c4v, c5v)
        LOADROW(ry3, d0, d1, d2, d3, d4, d5)
        LOADROW(ry4, e0, e1, e2, e3, e4, e5)
#undef LOADROW
    }

    // shared forgetful phase over the 20 shared elements (cols 1..4 of each row)
    float w0 = a1, w1 = a2, w2 = a3, w3 = a4;
    float w4 = b1, w5 = b2, w6 = b3, w7 = b4;
    float w8 = c1v, w9 = c2v, w10 = c3v, w11 = c4v;
    float w12 = d1, w13 = d2;

    sw14(w0, w1, w2, w3, w4, w5, w6, w7, w8, w9, w10, w11, w12, w13);
    w0 = d3;
    sw13(w0, w1, w2, w3, w4, w5, w6, w7, w8, w9, w10, w11, w12);
    w0 = d4;
    sw12(w0, w1, w2, w3, w4, w5, w6, w7, w8, w9, w10, w11);
    w0 = e1;
    sw11(w0, w1, w2, w3, w4, w5, w6, w7, w8, w9, w10);
    w0 = e2;
    sw10(w0, w1, w2, w3, w4, w5, w6, w7, w8, w9);
    w0 = e3;
    sw9(w0, w1, w2, w3, w4, w5, w6, w7, w8);
    w0 = e4;
    // survivors {w0..w7} = middle 8 (ranks 7..14) of the shared 20

    const float medL = tail5(w0, w1, w2, w3, w4, w5, w6, w7, a0, b0, c0v, d0, e0);
    const float medR = tail5(w0, w1, w2, w3, w4, w5, w6, w7, a5, b5, c5v, d5, e5);

    float2 res = make_float2(medL, medR);
    *reinterpret_cast<float2*>(out + ry2 + xL) = res;
}

extern "C" void kernel_launch(void* const* d_in, const int* in_sizes, int n_in,
                              void* d_out, int out_size, void* d_ws, size_t ws_size,
                              hipStream_t stream) {
    const float* img = (const float*)d_in[0];
    float* out = (float*)d_out;
    dim3 block(64, 4);
    dim3 grid((IMG_W / 2) / 64, IMG_H / 4);
    median5x5_kernel<<<grid, block, 0, stream>>>(img, out);
}

// Round 4
// 33.042 us; speedup vs baseline: 1.1346x; 1.1346x over previous
//
#include <hip/hip_runtime.h>

constexpr int IMG_H = 2048;
constexpr int IMG_W = 2048;

// compare-exchange via raw ISA min/max: exactly 2 VALU ops, no NaN-canonicalize
// bloat (inputs are finite). a=min, b=max.
#define CE(a, b) {                                              \
    float _mn, _mx;                                             \
    asm("v_min_f32 %0, %1, %2" : "=v"(_mn) : "v"(a), "v"(b));   \
    asm("v_max_f32 %0, %1, %2" : "=v"(_mx) : "v"(a), "v"(b));   \
    a = _mn; b = _mx;                                           \
}

__device__ __forceinline__ void sw14(float& a0, float& a1, float& a2, float& a3, float& a4,
                                     float& a5, float& a6, float& a7, float& a8, float& a9,
                                     float& a10, float& a11, float& a12, float& a13) {
    CE(a0, a13) CE(a1, a12) CE(a2, a11) CE(a3, a10) CE(a4, a9) CE(a5, a8) CE(a6, a7)
    CE(a0, a1) CE(a0, a2) CE(a0, a3) CE(a0, a4) CE(a0, a5) CE(a0, a6)
    CE(a6, a13) CE(a7, a13) CE(a8, a13) CE(a9, a13) CE(a10, a13) CE(a11, a13) CE(a12, a13)
}
__device__ __forceinline__ void sw13(float& a0, float& a1, float& a2, float& a3, float& a4,
                                     float& a5, float& a6, float& a7, float& a8, float& a9,
                                     float& a10, float& a11, float& a12) {
    CE(a0, a12) CE(a1, a11) CE(a2, a10) CE(a3, a9) CE(a4, a8) CE(a5, a7)
    CE(a0, a1) CE(a0, a2) CE(a0, a3) CE(a0, a4) CE(a0, a5) CE(a0, a6)
    CE(a6, a12) CE(a7, a12) CE(a8, a12) CE(a9, a12) CE(a10, a12) CE(a11, a12)
}
__device__ __forceinline__ void sw12(float& a0, float& a1, float& a2, float& a3, float& a4,
                                     float& a5, float& a6, float& a7, float& a8, float& a9,
                                     float& a10, float& a11) {
    CE(a0, a11) CE(a1, a10) CE(a2, a9) CE(a3, a8) CE(a4, a7) CE(a5, a6)
    CE(a0, a1) CE(a0, a2) CE(a0, a3) CE(a0, a4) CE(a0, a5)
    CE(a5, a11) CE(a6, a11) CE(a7, a11) CE(a8, a11) CE(a9, a11) CE(a10, a11)
}
__device__ __forceinline__ void sw11(float& a0, float& a1, float& a2, float& a3, float& a4,
                                     float& a5, float& a6, float& a7, float& a8, float& a9,
                                     float& a10) {
    CE(a0, a10) CE(a1, a9) CE(a2, a8) CE(a3, a7) CE(a4, a6)
    CE(a0, a1) CE(a0, a2) CE(a0, a3) CE(a0, a4) CE(a0, a5)
    CE(a5, a10) CE(a6, a10) CE(a7, a10) CE(a8, a10) CE(a9, a10)
}
__device__ __forceinline__ void sw10(float& a0, float& a1, float& a2, float& a3, float& a4,
                                     float& a5, float& a6, float& a7, float& a8, float& a9) {
    CE(a0, a9) CE(a1, a8) CE(a2, a7) CE(a3, a6) CE(a4, a5)
    CE(a0, a1) CE(a0, a2) CE(a0, a3) CE(a0, a4)
    CE(a4, a9) CE(a5, a9) CE(a6, a9) CE(a7, a9) CE(a8, a9)
}
__device__ __forceinline__ void sw9(float& a0, float& a1, float& a2, float& a3, float& a4,
                                    float& a5, float& a6, float& a7, float& a8) {
    CE(a0, a8) CE(a1, a7) CE(a2, a6) CE(a3, a5)
    CE(a0, a1) CE(a0, a2) CE(a0, a3) CE(a0, a4)
    CE(a4, a8) CE(a5, a8) CE(a6, a8) CE(a7, a8)
}
__device__ __forceinline__ void sw8(float& a0, float& a1, float& a2, float& a3, float& a4,
                                    float& a5, float& a6, float& a7) {
    CE(a0, a7) CE(a1, a6) CE(a2, a5) CE(a3, a4)
    CE(a0, a1) CE(a0, a2) CE(a0, a3)
    CE(a3, a7) CE(a4, a7) CE(a5, a7) CE(a6, a7)
}
__device__ __forceinline__ void sw7(float& a0, float& a1, float& a2, float& a3, float& a4,
                                    float& a5, float& a6) {
    CE(a0, a6) CE(a1, a5) CE(a2, a4)
    CE(a0, a1) CE(a0, a2) CE(a0, a3)
    CE(a3, a6) CE(a4, a6) CE(a5, a6)
}
__device__ __forceinline__ void sw6(float& a0, float& a1, float& a2, float& a3, float& a4,
                                    float& a5) {
    CE(a0, a5) CE(a1, a4) CE(a2, a3)
    CE(a0, a1) CE(a0, a2)
    CE(a2, a5) CE(a3, a5) CE(a4, a5)
}

// tail for one pixel: 8 shared survivors (ranks 7..14 of shared 20) + 5 private -> median
__device__ __forceinline__ float tail5(float l1, float l2, float l3, float l4, float l5,
                                       float l6, float l7, float l8,
                                       float p0, float p1, float p2, float p3, float p4) {
    float l0 = p0;
    sw9(l0, l1, l2, l3, l4, l5, l6, l7, l8);
    l0 = p1;
    sw8(l0, l1, l2, l3, l4, l5, l6, l7);
    l0 = p2;
    sw7(l0, l1, l2, l3, l4, l5, l6);
    l0 = p3;
    sw6(l0, l1, l2, l3, l4, l5);
    l0 = p4;
    // 5 survivors hold ranks 11..15 of 25 -> median of 5
    CE(l0, l1) CE(l3, l4) CE(l0, l3) CE(l1, l4)
    return __builtin_amdgcn_fmed3f(l1, l2, l3);
}

__global__ __launch_bounds__(256) void median5x5_kernel(const float* __restrict__ img,
                                                        float* __restrict__ out) {
    const int t = blockIdx.x * blockDim.x + threadIdx.x;  // pixel-pair index
    const int y = blockIdx.y * blockDim.y + threadIdx.y;
    const int xL = 2 * t;  // left pixel; right = xL+1

    // reflected row bases
    int r0 = y - 2, r1 = y - 1, r3 = y + 1, r4 = y + 2;
    r0 = (r0 < 0) ? -r0 : r0;
    r1 = (r1 < 0) ? -r1 : r1;
    r3 = (r3 >= IMG_H) ? 2 * IMG_H - 2 - r3 : r3;
    r4 = (r4 >= IMG_H) ? 2 * IMG_H - 2 - r4 : r4;
    const int ry0 = r0 * IMG_W, ry1 = r1 * IMG_W, ry2 = y * IMG_W,
              ry3 = r3 * IMG_W, ry4 = r4 * IMG_W;

    // reflected column indices xL-2 .. xL+3
    int c0 = xL - 2, c1 = xL - 1, c4 = xL + 2, c5 = xL + 3;
    c0 = (c0 < 0) ? -c0 : c0;
    c1 = (c1 < 0) ? -c1 : c1;
    c4 = (c4 >= IMG_W) ? 2 * IMG_W - 2 - c4 : c4;
    c5 = (c5 >= IMG_W) ? 2 * IMG_W - 2 - c5 : c5;
    const int c2 = xL, c3 = xL + 1;

    // shared 20 = cols c1..c4 x 5 rows. First 14 into working set, 6 deferred.
    float w0 = img[ry0 + c1], w1 = img[ry0 + c2], w2 = img[ry0 + c3], w3 = img[ry0 + c4];
    float w4 = img[ry1 + c1], w5 = img[ry1 + c2], w6 = img[ry1 + c3], w7 = img[ry1 + c4];
    float w8 = img[ry2 + c1], w9 = img[ry2 + c2], w10 = img[ry2 + c3], w11 = img[ry2 + c4];
    float w12 = img[ry3 + c1], w13 = img[ry3 + c2];
    float e14 = img[ry3 + c3], e15 = img[ry3 + c4];
    float e16 = img[ry4 + c1], e17 = img[ry4 + c2], e18 = img[ry4 + c3], e19 = img[ry4 + c4];
    // private columns
    float p0 = img[ry0 + c0], p1 = img[ry1 + c0], p2 = img[ry2 + c0], p3 = img[ry3 + c0],
          p4 = img[ry4 + c0];
    float q0 = img[ry0 + c5], q1 = img[ry1 + c5], q2 = img[ry2 + c5], q3 = img[ry3 + c5],
          q4 = img[ry4 + c5];

    // shared forgetful phase: sweeps 14..9 over the 20 shared elements.
    sw14(w0, w1, w2, w3, w4, w5, w6, w7, w8, w9, w10, w11, w12, w13);
    w0 = e14;
    sw13(w0, w1, w2, w3, w4, w5, w6, w7, w8, w9, w10, w11, w12);
    w0 = e15;
    sw12(w0, w1, w2, w3, w4, w5, w6, w7, w8, w9, w10, w11);
    w0 = e16;
    sw11(w0, w1, w2, w3, w4, w5, w6, w7, w8, w9, w10);
    w0 = e17;
    sw10(w0, w1, w2, w3, w4, w5, w6, w7, w8, w9);
    w0 = e18;
    sw9(w0, w1, w2, w3, w4, w5, w6, w7, w8);
    w0 = e19;
    // survivors {w0..w7} = middle 8 (ranks 7..14) of the shared 20

    const float medL = tail5(w0, w1, w2, w3, w4, w5, w6, w7, p0, p1, p2, p3, p4);
    const float medR = tail5(w0, w1, w2, w3, w4, w5, w6, w7, q0, q1, q2, q3, q4);

    float2 res = make_float2(medL, medR);
    *reinterpret_cast<float2*>(out + ry2 + xL) = res;
}

extern "C" void kernel_launch(void* const* d_in, const int* in_sizes, int n_in,
                              void* d_out, int out_size, void* d_ws, size_t ws_size,
                              hipStream_t stream) {
    const float* img = (const float*)d_in[0];
    float* out = (float*)d_out;
    dim3 block(64, 4);
    dim3 grid((IMG_W / 2) / 64, IMG_H / 4);
    median5x5_kernel<<<grid, block, 0, stream>>>(img, out);
}

// Round 5
// 30.722 us; speedup vs baseline: 1.2203x; 1.0755x over previous
//
#include <hip/hip_runtime.h>

constexpr int IMG_H = 2048;
constexpr int IMG_W = 2048;

// compare-exchange: a=min, b=max (2 VALU)
#define CE(a, b) {                                              \
    float _mn, _mx;                                             \
    asm("v_min_f32 %0, %1, %2" : "=v"(_mn) : "v"(a), "v"(b));   \
    asm("v_max_f32 %0, %1, %2" : "=v"(_mx) : "v"(a), "v"(b));   \
    a = _mn; b = _mx;                                           \
}

// 3-element sort via VOP3 3-input ops: a=min, b=med, c=max (3 VALU)
#define SORT3(a, b, c) {                                                      \
    float _n, _d, _x;                                                         \
    asm("v_min3_f32 %0, %1, %2, %3" : "=v"(_n) : "v"(a), "v"(b), "v"(c));     \
    asm("v_med3_f32 %0, %1, %2, %3" : "=v"(_d) : "v"(a), "v"(b), "v"(c));     \
    asm("v_max3_f32 %0, %1, %2, %3" : "=v"(_x) : "v"(a), "v"(b), "v"(c));     \
    a = _n; b = _d; c = _x;                                                   \
}

// minmax sweeps built from sort3 groups + sort3/CE tournaments.
// Post: min in first slot, max in last slot, multiset preserved.
__device__ __forceinline__ void sw14(float& a0, float& a1, float& a2, float& a3, float& a4,
                                     float& a5, float& a6, float& a7, float& a8, float& a9,
                                     float& a10, float& a11, float& a12, float& a13) {
    SORT3(a0, a1, a2) SORT3(a3, a4, a5) SORT3(a6, a7, a8) SORT3(a9, a10, a11) CE(a12, a13)
    SORT3(a0, a3, a6) SORT3(a0, a9, a12)   // min -> a0
    SORT3(a2, a5, a8) SORT3(a8, a11, a13)  // max -> a13
}
__device__ __forceinline__ void sw13(float& a0, float& a1, float& a2, float& a3, float& a4,
                                     float& a5, float& a6, float& a7, float& a8, float& a9,
                                     float& a10, float& a11, float& a12) {
    SORT3(a0, a1, a2) SORT3(a3, a4, a5) SORT3(a6, a7, a8) SORT3(a9, a10, a11)  // a12 loner
    SORT3(a0, a3, a6) SORT3(a0, a9, a12)   // min -> a0 (a12 keeps any global max)
    SORT3(a2, a5, a8) SORT3(a8, a11, a12)  // max -> a12
}
__device__ __forceinline__ void sw12(float& a0, float& a1, float& a2, float& a3, float& a4,
                                     float& a5, float& a6, float& a7, float& a8, float& a9,
                                     float& a10, float& a11) {
    SORT3(a0, a1, a2) SORT3(a3, a4, a5) SORT3(a6, a7, a8) SORT3(a9, a10, a11)
    SORT3(a0, a3, a6) CE(a0, a9)           // min -> a0
    SORT3(a2, a5, a8) CE(a8, a11)          // max -> a11
}
__device__ __forceinline__ void sw11(float& a0, float& a1, float& a2, float& a3, float& a4,
                                     float& a5, float& a6, float& a7, float& a8, float& a9,
                                     float& a10) {
    SORT3(a0, a1, a2) SORT3(a3, a4, a5) SORT3(a6, a7, a8) CE(a9, a10)
    SORT3(a0, a3, a6) CE(a0, a9)           // min -> a0
    SORT3(a2, a5, a8) CE(a8, a10)          // max -> a10
}
__device__ __forceinline__ void sw10(float& a0, float& a1, float& a2, float& a3, float& a4,
                                     float& a5, float& a6, float& a7, float& a8, float& a9) {
    SORT3(a0, a1, a2) SORT3(a3, a4, a5) SORT3(a6, a7, a8)  // a9 loner
    SORT3(a0, a3, a6) CE(a0, a9)           // min -> a0 (a9 keeps any global max)
    SORT3(a2, a5, a8) CE(a8, a9)           // max -> a9
}
__device__ __forceinline__ void sw9(float& a0, float& a1, float& a2, float& a3, float& a4,
                                    float& a5, float& a6, float& a7, float& a8) {
    SORT3(a0, a1, a2) SORT3(a3, a4, a5) SORT3(a6, a7, a8)
    SORT3(a0, a3, a6)                      // min -> a0
    SORT3(a2, a5, a8)                      // max -> a8
}
__device__ __forceinline__ void sw8(float& a0, float& a1, float& a2, float& a3, float& a4,
                                    float& a5, float& a6, float& a7) {
    SORT3(a0, a1, a2) SORT3(a3, a4, a5) CE(a6, a7)
    SORT3(a0, a3, a6)                      // min -> a0
    SORT3(a2, a5, a7)                      // max -> a7
}
__device__ __forceinline__ void sw7(float& a0, float& a1, float& a2, float& a3, float& a4,
                                    float& a5, float& a6) {
    SORT3(a0, a1, a2) SORT3(a3, a4, a5)    // a6 loner
    SORT3(a0, a3, a6)                      // min -> a0 (a6 keeps any global max)
    SORT3(a2, a5, a6)                      // max -> a6
}
__device__ __forceinline__ void sw6(float& a0, float& a1, float& a2, float& a3, float& a4,
                                    float& a5) {
    SORT3(a0, a1, a2) SORT3(a3, a4, a5)
    CE(a0, a3)                             // min -> a0
    CE(a2, a5)                             // max -> a5
}

// exact median of 5: discard min of pair-mins and max of pair-maxes, med3 rest
__device__ __forceinline__ float med5(float l0, float l1, float l2, float l3, float l4) {
    CE(l0, l1) CE(l2, l3)
    float a, b;
    asm("v_max_f32 %0, %1, %2" : "=v"(a) : "v"(l0), "v"(l2));
    asm("v_min_f32 %0, %1, %2" : "=v"(b) : "v"(l1), "v"(l3));
    return __builtin_amdgcn_fmed3f(a, b, l4);
}

// tail for one pixel: 8 shared survivors (middle of shared 20) + 5 private -> median of 25
__device__ __forceinline__ float tail5(float l1, float l2, float l3, float l4, float l5,
                                       float l6, float l7, float l8,
                                       float p0, float p1, float p2, float p3, float p4) {
    float l0 = p0;
    sw9(l0, l1, l2, l3, l4, l5, l6, l7, l8);
    l0 = p1;
    sw8(l0, l1, l2, l3, l4, l5, l6, l7);
    l0 = p2;
    sw7(l0, l1, l2, l3, l4, l5, l6);
    l0 = p3;
    sw6(l0, l1, l2, l3, l4, l5);
    l0 = p4;
    return med5(l0, l1, l2, l3, l4);  // survivors are ranks 11..15 of 25
}

__global__ __launch_bounds__(256) void median5x5_kernel(const float* __restrict__ img,
                                                        float* __restrict__ out) {
    const int t = blockIdx.x * blockDim.x + threadIdx.x;  // pixel-pair index
    const int y = blockIdx.y * blockDim.y + threadIdx.y;
    const int xL = 2 * t;  // left pixel; right = xL+1

    // reflected row bases
    int r0 = y - 2, r1 = y - 1, r3 = y + 1, r4 = y + 2;
    r0 = (r0 < 0) ? -r0 : r0;
    r1 = (r1 < 0) ? -r1 : r1;
    r3 = (r3 >= IMG_H) ? 2 * IMG_H - 2 - r3 : r3;
    r4 = (r4 >= IMG_H) ? 2 * IMG_H - 2 - r4 : r4;
    const int ry0 = r0 * IMG_W, ry1 = r1 * IMG_W, ry2 = y * IMG_W,
              ry3 = r3 * IMG_W, ry4 = r4 * IMG_W;

    // reflected column indices xL-2 .. xL+3
    int c0 = xL - 2, c1 = xL - 1, c4 = xL + 2, c5 = xL + 3;
    c0 = (c0 < 0) ? -c0 : c0;
    c1 = (c1 < 0) ? -c1 : c1;
    c4 = (c4 >= IMG_W) ? 2 * IMG_W - 2 - c4 : c4;
    c5 = (c5 >= IMG_W) ? 2 * IMG_W - 2 - c5 : c5;
    const int c2 = xL, c3 = xL + 1;

    // shared 20 = cols c1..c4 x 5 rows. First 14 into working set, 6 deferred.
    float w0 = img[ry0 + c1], w1 = img[ry0 + c2], w2 = img[ry0 + c3], w3 = img[ry0 + c4];
    float w4 = img[ry1 + c1], w5 = img[ry1 + c2], w6 = img[ry1 + c3], w7 = img[ry1 + c4];
    float w8 = img[ry2 + c1], w9 = img[ry2 + c2], w10 = img[ry2 + c3], w11 = img[ry2 + c4];
    float w12 = img[ry3 + c1], w13 = img[ry3 + c2];
    float e14 = img[ry3 + c3], e15 = img[ry3 + c4];
    float e16 = img[ry4 + c1], e17 = img[ry4 + c2], e18 = img[ry4 + c3], e19 = img[ry4 + c4];
    // private columns
    float p0 = img[ry0 + c0], p1 = img[ry1 + c0], p2 = img[ry2 + c0], p3 = img[ry3 + c0],
          p4 = img[ry4 + c0];
    float q0 = img[ry0 + c5], q1 = img[ry1 + c5], q2 = img[ry2 + c5], q3 = img[ry3 + c5],
          q4 = img[ry4 + c5];

    // shared forgetful phase: sweeps 14..9 over the 20 shared elements.
    // Discard validity: (s-1) in-set witnesses + prior opposite-side discards = 13.
    sw14(w0, w1, w2, w3, w4, w5, w6, w7, w8, w9, w10, w11, w12, w13);
    w0 = e14;
    sw13(w0, w1, w2, w3, w4, w5, w6, w7, w8, w9, w10, w11, w12);
    w0 = e15;
    sw12(w0, w1, w2, w3, w4, w5, w6, w7, w8, w9, w10, w11);
    w0 = e16;
    sw11(w0, w1, w2, w3, w4, w5, w6, w7, w8, w9, w10);
    w0 = e17;
    sw10(w0, w1, w2, w3, w4, w5, w6, w7, w8, w9);
    w0 = e18;
    sw9(w0, w1, w2, w3, w4, w5, w6, w7, w8);
    w0 = e19;
    // survivors {w0..w7} = middle 8 (ranks 7..14) of the shared 20

    const float medL = tail5(w0, w1, w2, w3, w4, w5, w6, w7, p0, p1, p2, p3, p4);
    const float medR = tail5(w0, w1, w2, w3, w4, w5, w6, w7, q0, q1, q2, q3, q4);

    float2 res = make_float2(medL, medR);
    *reinterpret_cast<float2*>(out + ry2 + xL) = res;
}

extern "C" void kernel_launch(void* const* d_in, const int* in_sizes, int n_in,
                              void* d_out, int out_size, void* d_ws, size_t ws_size,
                              hipStream_t stream) {
    const float* img = (const float*)d_in[0];
    float* out = (float*)d_out;
    dim3 block(64, 4);
    dim3 grid((IMG_W / 2) / 64, IMG_H / 4);
    median5x5_kernel<<<grid, block, 0, stream>>>(img, out);
}